// Round 5
// baseline (81.121 us; speedup 1.0000x reference)
//
#include <hip/hip_runtime.h>

// SpatialTransformer: batched affine warp + trilinear resample.
// vol: [4,160,160,160,2] fp32, trf: [4,3,4] fp32 -> out: [4,160,160,160,2] fp32.
// Sample coord = M * (x - c) + t + c, c = (160-1)/2 = 79.5, clamped to [0,159].
//
// r2: XCD chunked swizzle (FETCH 252.7->48.9 MB).
// r3: z-corner pairing: 8 -> 4 gathers/voxel (98.5 -> 73.8 us).
// r4: 2 voxels/thread along k (halve waves, 8 outstanding gathers, amortize
//     decompose+affine), drop sel_hi (clamped lower corner has weight exactly
//     0, so unconditionally using q.lo is exact), 16B NT store.
// r5: fix compile — __builtin_nontemporal_store needs a clang ext_vector
//     type, not HIP's float4 class.

constexpr int D = 160, H = 160, W = 160, C = 2;
constexpr unsigned VOX_PER_B = D * H * W;          // 4,096,000
constexpr unsigned TOTAL = 4u * VOX_PER_B;         // 16,384,000
constexpr unsigned PAIRS = TOTAL / 2u;             // 8,192,000 (k-pairs)
constexpr unsigned NBLOCKS = PAIRS / 256u;         // 32,000 (exact)
constexpr unsigned NXCD = 8;
constexpr unsigned CHUNK = NBLOCKS / NXCD;         // 4,000

typedef float f32x4 __attribute__((ext_vector_type(4)));

struct VPair { float2 lo, hi; };  // 16B: voxels [zb] and [zb+1] of one row

// trilinear sample at (lx,ly,lz) with reference clip semantics.
__device__ __forceinline__ float2 sample_tri(const float2* __restrict__ vb,
                                             float lx, float ly, float lz)
{
    const float mx = 159.0f;
    lx = fminf(fmaxf(lx, 0.0f), mx);
    ly = fminf(fmaxf(ly, 0.0f), mx);
    lz = fminf(fmaxf(lz, 0.0f), mx);

    float fx0 = floorf(lx), fy0 = floorf(ly), fz0 = floorf(lz);
    float fx1 = fminf(fx0 + 1.0f, mx);
    float fy1 = fminf(fy0 + 1.0f, mx);
    float fz1 = fminf(fz0 + 1.0f, mx);

    int ix0 = (int)fx0, iy0 = (int)fy0, iz0 = (int)fz0;
    int ix1 = (int)fx1, iy1 = (int)fy1;

    // voxelmorph convention: w_lo = loc1 - loc (weight of LOWER corner)
    float wxl = fx1 - lx, wyl = fy1 - ly, wzl = fz1 - lz;
    float wxh = 1.0f - wxl, wyh = 1.0f - wyl, wzh = 1.0f - wzl;

    // z-pair base: iz1 == zb+1 always. In the clamp case (iz0==159, zb=158)
    // the lower-corner weight wzl is EXACTLY 0, so using q.lo (=v158, finite)
    // contributes 0 and the result equals ref's v159. No select needed.
    int zb = min(iz0, W - 2);

    int r0 = ix0 * H, r1 = ix1 * H;
    int p00 = (r0 + iy0) * W + zb, p01 = (r0 + iy1) * W + zb;
    int p10 = (r1 + iy0) * W + zb, p11 = (r1 + iy1) * W + zb;

    VPair q00 = *(const VPair*)(vb + p00);
    VPair q01 = *(const VPair*)(vb + p01);
    VPair q10 = *(const VPair*)(vb + p10);
    VPair q11 = *(const VPair*)(vb + p11);

    // factorized trilinear: z -> y -> x (exact: wzh = 1-wzl etc.)
    float zx00 = q00.lo.x * wzl + q00.hi.x * wzh, zy00 = q00.lo.y * wzl + q00.hi.y * wzh;
    float zx01 = q01.lo.x * wzl + q01.hi.x * wzh, zy01 = q01.lo.y * wzl + q01.hi.y * wzh;
    float zx10 = q10.lo.x * wzl + q10.hi.x * wzh, zy10 = q10.lo.y * wzl + q10.hi.y * wzh;
    float zx11 = q11.lo.x * wzl + q11.hi.x * wzh, zy11 = q11.lo.y * wzl + q11.hi.y * wzh;

    float yx0 = zx00 * wyl + zx01 * wyh, yy0 = zy00 * wyl + zy01 * wyh;
    float yx1 = zx10 * wyl + zx11 * wyh, yy1 = zy10 * wyl + zy11 * wyh;

    float2 o;
    o.x = yx0 * wxl + yx1 * wxh;
    o.y = yy0 * wxl + yy1 * wxh;
    return o;
}

__global__ __launch_bounds__(256) void st_affine_trilinear(
    const float* __restrict__ vol,
    const float* __restrict__ trf,
    float* __restrict__ out)
{
    // bijective chunked XCD swizzle: each XCD gets a contiguous output slab.
    unsigned bid = blockIdx.x;
    unsigned swz = (bid & (NXCD - 1)) * CHUNK + (bid >> 3);
    unsigned tid = swz * 256u + threadIdx.x;   // pair index, [0, PAIRS)

    // decompose: tid -> (b, i, j, kp); thread handles k = 2*kp and 2*kp+1.
    unsigned kp = tid % (unsigned)(W / 2);
    unsigned t = tid / (unsigned)(W / 2);
    unsigned j = t % (unsigned)H;
    t /= (unsigned)H;
    unsigned i = t % (unsigned)D;
    unsigned b = t / (unsigned)D;
    unsigned k = kp * 2u;

    // affine row-major [3][4]; b is wave-uniform
    const float* m = trf + b * 12u;
    float m00 = m[0], m01 = m[1], m02 = m[2],  m03 = m[3];
    float m10 = m[4], m11 = m[5], m12 = m[6],  m13 = m[7];
    float m20 = m[8], m21 = m[9], m22 = m[10], m23 = m[11];

    const float cc = 79.5f;
    float xc = (float)i - cc, yc = (float)j - cc, zc = (float)k - cc;

    float lx0 = fmaf(m00, xc, fmaf(m01, yc, fmaf(m02, zc, m03 + cc)));
    float ly0 = fmaf(m10, xc, fmaf(m11, yc, fmaf(m12, zc, m13 + cc)));
    float lz0 = fmaf(m20, xc, fmaf(m21, yc, fmaf(m22, zc, m23 + cc)));
    // voxel k+1: add the z-column of M. vs ref's independent fmaf chain this
    // differs by ~1 ulp of ~20 (~2e-6) — far under the 8.4e-2 threshold.
    float lx1 = lx0 + m02, ly1 = ly0 + m12, lz1 = lz0 + m22;

    const float2* vb = (const float2*)(vol) + (size_t)b * VOX_PER_B;

    float2 o0 = sample_tri(vb, lx0, ly0, lz0);
    float2 o1 = sample_tri(vb, lx1, ly1, lz1);

    // one 16B non-temporal store for both voxels (out stays out of L2/L3).
    f32x4 o = { o0.x, o0.y, o1.x, o1.y };
    __builtin_nontemporal_store(o, (f32x4*)out + tid);
}

extern "C" void kernel_launch(void* const* d_in, const int* in_sizes, int n_in,
                              void* d_out, int out_size, void* d_ws, size_t ws_size,
                              hipStream_t stream) {
    const float* vol = (const float*)d_in[0];
    const float* trf = (const float*)d_in[1];
    float* out = (float*)d_out;

    st_affine_trilinear<<<NBLOCKS, 256, 0, stream>>>(vol, trf, out);
}

// Round 6
// 59.415 us; speedup vs baseline: 1.3653x; 1.3653x over previous
//
#include <hip/hip_runtime.h>

// SpatialTransformer: batched affine warp + trilinear resample.
// vol: [4,160,160,160,2] fp32, trf: [4,3,4] fp32 -> out: [4,160,160,160,2] fp32.
// Sample coord = M * (x - c) + t + c, c = (160-1)/2 = 79.5, clamped to [0,159].
//
// r2: XCD chunked swizzle (FETCH 252.7->48.9 MB).
// r3: z-corner pairing: 8 -> 4 gathers/voxel (98.5 -> 73.8 us).
// r4/r5: 2 voxels/thread REGRESSED (81 us): doubled per-gather lane footprint
//        and register-serialized loads. Reverted.
// r6: block-uniform scalar b -> matrix loads become s_load (SGPR), removing
//     12 per-lane VMEM broadcasts per wave (12 of ~17 VMEM instrs). Also
//     drop sel_hi selects (clamped lower-corner weight is exactly 0).

constexpr int D = 160, H = 160, W = 160, C = 2;
constexpr unsigned VOX_PER_B = D * H * W;          // 4,096,000
constexpr unsigned TOTAL = 4u * VOX_PER_B;         // 16,384,000
constexpr unsigned NBLOCKS = TOTAL / 256u;         // 64,000 (exact)
constexpr unsigned BLOCKS_PER_VOL = VOX_PER_B / 256u;  // 16,000 (exact)
constexpr unsigned NXCD = 8;
constexpr unsigned CHUNK = NBLOCKS / NXCD;         // 8,000

struct VPair { float2 lo, hi; };  // 16B: voxels [zb] and [zb+1] of one row

__global__ __launch_bounds__(256) void st_affine_trilinear(
    const float* __restrict__ vol,
    const float* __restrict__ trf,
    float* __restrict__ out)
{
    // bijective chunked XCD swizzle: each XCD gets a contiguous output slab.
    unsigned bid = blockIdx.x;
    unsigned swz = (bid & (NXCD - 1)) * CHUNK + (bid >> 3);

    // b is BLOCK-uniform (16000 blocks per volume, exact): scalar-side
    // computation keeps b and the matrix in SGPRs -> s_load, no VMEM.
    unsigned b  = swz / BLOCKS_PER_VOL;
    unsigned rv = swz - b * BLOCKS_PER_VOL;        // block index within volume

    unsigned lt = rv * 256u + threadIdx.x;          // voxel index within volume
    // decompose: lt -> (i, j, k); consecutive threads walk k (coalesced).
    unsigned k = lt % (unsigned)W;
    unsigned t = lt / (unsigned)W;
    unsigned j = t % (unsigned)H;
    unsigned i = t / (unsigned)H;

    // affine row-major [3][4]; b uniform -> these are scalar loads.
    const float* m = trf + b * 12u;
    float m00 = m[0], m01 = m[1], m02 = m[2],  m03 = m[3];
    float m10 = m[4], m11 = m[5], m12 = m[6],  m13 = m[7];
    float m20 = m[8], m21 = m[9], m22 = m[10], m23 = m[11];

    const float cc = 79.5f;
    float xc = (float)i - cc, yc = (float)j - cc, zc = (float)k - cc;

    float lx = fmaf(m00, xc, fmaf(m01, yc, fmaf(m02, zc, m03 + cc)));
    float ly = fmaf(m10, xc, fmaf(m11, yc, fmaf(m12, zc, m13 + cc)));
    float lz = fmaf(m20, xc, fmaf(m21, yc, fmaf(m22, zc, m23 + cc)));

    const float mx = 159.0f;
    lx = fminf(fmaxf(lx, 0.0f), mx);
    ly = fminf(fmaxf(ly, 0.0f), mx);
    lz = fminf(fmaxf(lz, 0.0f), mx);

    float fx0 = floorf(lx), fy0 = floorf(ly), fz0 = floorf(lz);
    float fx1 = fminf(fx0 + 1.0f, mx);
    float fy1 = fminf(fy0 + 1.0f, mx);
    float fz1 = fminf(fz0 + 1.0f, mx);

    int ix0 = (int)fx0, iy0 = (int)fy0, iz0 = (int)fz0;
    int ix1 = (int)fx1, iy1 = (int)fy1;

    // voxelmorph convention: w_lo = loc1 - loc (weight of LOWER corner)
    float wxl = fx1 - lx, wyl = fy1 - ly, wzl = fz1 - lz;
    float wxh = 1.0f - wxl, wyh = 1.0f - wyl, wzh = 1.0f - wzl;

    const float2* vb = (const float2*)(vol) + (size_t)b * VOX_PER_B;

    // z-pair base: iz1 == zb+1 always. In the clamp case (iz0==159, zb=158)
    // the lower-corner weight wzl is EXACTLY 0, so q.lo (=v158, finite)
    // contributes nothing and the result equals ref's v159. No select needed.
    int zb = min(iz0, W - 2);

    int r0 = ix0 * H, r1 = ix1 * H;
    int p00 = (r0 + iy0) * W + zb, p01 = (r0 + iy1) * W + zb;
    int p10 = (r1 + iy0) * W + zb, p11 = (r1 + iy1) * W + zb;

    VPair q00 = *(const VPair*)(vb + p00);
    VPair q01 = *(const VPair*)(vb + p01);
    VPair q10 = *(const VPair*)(vb + p10);
    VPair q11 = *(const VPair*)(vb + p11);

    // factorized trilinear: z -> y -> x (exact: wzh = 1-wzl etc.)
    float zx00 = q00.lo.x * wzl + q00.hi.x * wzh, zy00 = q00.lo.y * wzl + q00.hi.y * wzh;
    float zx01 = q01.lo.x * wzl + q01.hi.x * wzh, zy01 = q01.lo.y * wzl + q01.hi.y * wzh;
    float zx10 = q10.lo.x * wzl + q10.hi.x * wzh, zy10 = q10.lo.y * wzl + q10.hi.y * wzh;
    float zx11 = q11.lo.x * wzl + q11.hi.x * wzh, zy11 = q11.lo.y * wzl + q11.hi.y * wzh;

    float yx0 = zx00 * wyl + zx01 * wyh, yy0 = zy00 * wyl + zy01 * wyh;
    float yx1 = zx10 * wyl + zx11 * wyh, yy1 = zy10 * wyl + zy11 * wyh;

    float ox = yx0 * wxl + yx1 * wxh;
    float oy = yy0 * wxl + yy1 * wxh;

    // non-temporal streaming store: keep the 131 MB output out of L2/L3.
    float2 o; o.x = ox; o.y = oy;
    double od;
    __builtin_memcpy(&od, &o, 8);
    unsigned gtid = swz * 256u + threadIdx.x;
    __builtin_nontemporal_store(od, (double*)out + gtid);
}

extern "C" void kernel_launch(void* const* d_in, const int* in_sizes, int n_in,
                              void* d_out, int out_size, void* d_ws, size_t ws_size,
                              hipStream_t stream) {
    const float* vol = (const float*)d_in[0];
    const float* trf = (const float*)d_in[1];
    float* out = (float*)d_out;

    st_affine_trilinear<<<NBLOCKS, 256, 0, stream>>>(vol, trf, out);
}